// Round 9
// baseline (334.959 us; speedup 1.0000x reference)
//
#include <hip/hip_runtime.h>
#include <hip/hip_bf16.h>

#define NROWS 8192
#define DIM 512

typedef __attribute__((ext_vector_type(8))) short bf16x8;
typedef __attribute__((ext_vector_type(4))) float f32x4;
typedef __attribute__((ext_vector_type(8))) unsigned short u16x8;

__device__ __forceinline__ float bf2f(unsigned short u) {
    return __uint_as_float(((unsigned int)u) << 16);
}
__device__ __forceinline__ unsigned short f2bf(float f) {
    unsigned int b = __float_as_uint(f);
    return (unsigned short)((b + 0x7FFFu + ((b >> 16) & 1u)) >> 16);
}
// monotone float->uint key
__device__ __forceinline__ unsigned int fkey(float f) {
    unsigned int b = __float_as_uint(f);
    return (b & 0x80000000u) ? ~b : (b | 0x80000000u);
}

// ---------------------------------------------------------------- k_prep
__global__ __launch_bounds__(256) void k_prep(const float* __restrict__ xs,
                                              unsigned short* __restrict__ hi,
                                              unsigned short* __restrict__ mo,
                                              float* __restrict__ sq,
                                              unsigned long long* __restrict__ nn) {
    const int wave = threadIdx.x >> 6, lane = threadIdx.x & 63;
    const int row = blockIdx.x * 4 + wave;
    const float4* xr = (const float4*)(xs + (size_t)row * DIM);
    const float4 a = xr[2 * lane], b = xr[2 * lane + 1];
    float v[8] = {a.x, a.y, a.z, a.w, b.x, b.y, b.z, b.w};
    u16x8 h, l;
    float s = 0.f;
#pragma unroll
    for (int i = 0; i < 8; ++i) {
        const unsigned short hs = f2bf(v[i]);
        h[i] = hs;
        l[i] = f2bf(v[i] - bf2f(hs));
        s = fmaf(v[i], v[i], s);
    }
    *(u16x8*)(hi + (size_t)row * DIM + lane * 8) = h;
    *(u16x8*)(mo + (size_t)row * DIM + lane * 8) = l;
#pragma unroll
    for (int d = 32; d; d >>= 1) s += __shfl_xor(s, d);
    if (lane == 0) { sq[row] = s; nn[row] = ~0ull; }
}

// ---------------------------------------------------------------- k_nn
// Triangle pair-space, XCD-supertiled. Split-bf16 3-MFMA, BK=32.
// Staging now via global_load_lds (16B DMA): wave w stages plane w in 8
// stripes of 16 rows; lane mapping rl=lane>>2, c=((lane&3)-(rl>>1))&3 makes
// the linear DMA landing (base+lane*16) equal the conflict-free swizzled
// layout, so read offsets are unchanged and conflicts stay 0.
__global__ __launch_bounds__(256) void k_nn(const unsigned short* __restrict__ xh,
                                            const unsigned short* __restrict__ xl,
                                            const float* __restrict__ sq,
                                            unsigned long long* __restrict__ nn) {
    __shared__ __align__(16) unsigned short lAh[128 * 32];
    __shared__ __align__(16) unsigned short lAl[128 * 32];
    __shared__ __align__(16) unsigned short lBh[128 * 32];
    __shared__ __align__(16) unsigned short lBl[128 * 32];
    const int tid = threadIdx.x;
    const int wave = tid >> 6, lane = tid & 63, quad = lane >> 4, ln = lane & 15;
    const int b = blockIdx.x;
    const int xcd = b & 7, w = b >> 3;
    const int s = w >> 3, bil = w & 7;
    const int bi = xcd * 8 + bil;
    const int bj = (bi + s) & 63;
    const int i0 = bi * 128, j0 = bj * 128;
    const int m_off = (wave & 1) * 64, n_off = (wave >> 1) * 64;

    // per-wave staging assignment: one plane per wave
    const unsigned short* gsrc;
    unsigned short* lbase;
    int trow;
    if (wave == 0)      { gsrc = xh; lbase = lAh; trow = i0; }
    else if (wave == 1) { gsrc = xl; lbase = lAl; trow = i0; }
    else if (wave == 2) { gsrc = xh; lbase = lBh; trow = j0; }
    else                { gsrc = xl; lbase = lBl; trow = j0; }
    const int rl = lane >> 2;                       // row within stripe
    const int cc = ((lane & 3) - (rl >> 1)) & 3;    // chunk permutation
    const unsigned short* gp = gsrc + (size_t)(trow + rl) * DIM + cc * 8;

    int aoff[4], boff[4];
#pragma unroll
    for (int ms = 0; ms < 4; ++ms) {
        const int r = m_off + ms * 16 + ln;
        aoff[ms] = r * 32 + ((quad + (r >> 1)) & 3) * 8;
    }
#pragma unroll
    for (int ns = 0; ns < 4; ++ns) {
        const int r = n_off + ns * 16 + ln;
        boff[ns] = r * 32 + ((quad + (r >> 1)) & 3) * 8;
    }

    f32x4 acc[4][4];
#pragma unroll
    for (int a = 0; a < 4; ++a)
#pragma unroll
        for (int c = 0; c < 4; ++c) acc[a][c] = (f32x4){0.f, 0.f, 0.f, 0.f};

    for (int kt = 0; kt < 16; ++kt) {
        __syncthreads();  // previous iter's reads complete
#pragma unroll
        for (int st = 0; st < 8; ++st)
            __builtin_amdgcn_global_load_lds(
                (const __attribute__((address_space(1))) void*)(gp + (size_t)(st * 16) * DIM + kt * 32),
                (__attribute__((address_space(3))) void*)(lbase + st * 512), 16, 0, 0);
        __syncthreads();  // drains vmcnt + barrier: LDS fully populated
        bf16x8 ah[4], al[4], bh[4], bl[4];
#pragma unroll
        for (int ms = 0; ms < 4; ++ms) {
            ah[ms] = *(const bf16x8*)(lAh + aoff[ms]);
            al[ms] = *(const bf16x8*)(lAl + aoff[ms]);
        }
#pragma unroll
        for (int ns = 0; ns < 4; ++ns) {
            bh[ns] = *(const bf16x8*)(lBh + boff[ns]);
            bl[ns] = *(const bf16x8*)(lBl + boff[ns]);
        }
#pragma unroll
        for (int ms = 0; ms < 4; ++ms)
#pragma unroll
            for (int ns = 0; ns < 4; ++ns) {
                acc[ms][ns] = __builtin_amdgcn_mfma_f32_16x16x32_bf16(
                    ah[ms], bh[ns], acc[ms][ns], 0, 0, 0);
                acc[ms][ns] = __builtin_amdgcn_mfma_f32_16x16x32_bf16(
                    ah[ms], bl[ns], acc[ms][ns], 0, 0, 0);
                acc[ms][ns] = __builtin_amdgcn_mfma_f32_16x16x32_bf16(
                    al[ms], bh[ns], acc[ms][ns], 0, 0, 0);
            }
    }
    const bool diag = (i0 == j0);
    float sqj[4];
#pragma unroll
    for (int ns = 0; ns < 4; ++ns) sqj[ns] = sq[j0 + n_off + ns * 16 + ln];
    float sqi[4][4];
#pragma unroll
    for (int ms = 0; ms < 4; ++ms)
#pragma unroll
        for (int v = 0; v < 4; ++v)
            sqi[ms][v] = sq[i0 + m_off + ms * 16 + quad * 4 + v];

#pragma unroll
    for (int ms = 0; ms < 4; ++ms)
#pragma unroll
        for (int v = 0; v < 4; ++v) {
            const int gi = i0 + m_off + ms * 16 + quad * 4 + v;
            float mv = __builtin_inff();
            int mi = 0;
#pragma unroll
            for (int ns = 0; ns < 4; ++ns) {
                const int gj = j0 + n_off + ns * 16 + ln;
                float d2 = fmaf(-2.f, acc[ms][ns][v], sqj[ns]);
                if (diag && gj == gi) d2 = __builtin_inff();
                if (d2 < mv) { mv = d2; mi = gj; }
            }
            unsigned long long p =
                (((unsigned long long)fkey(mv)) << 32) | (unsigned int)mi;
#pragma unroll
            for (int d = 1; d < 16; d <<= 1) {
                unsigned long long o = __shfl_xor(p, d);
                p = (o < p) ? o : p;
            }
            if (ln == 0) atomicMin(&nn[gi], p);
        }
#pragma unroll
    for (int ns = 0; ns < 4; ++ns) {
        const int gj = j0 + n_off + ns * 16 + ln;
        unsigned long long p = ~0ull;
#pragma unroll
        for (int ms = 0; ms < 4; ++ms)
#pragma unroll
            for (int v = 0; v < 4; ++v) {
                const int gi = i0 + m_off + ms * 16 + quad * 4 + v;
                const float d2 = fmaf(-2.f, acc[ms][ns][v], sqi[ms][v]);
                const unsigned long long q =
                    (((unsigned long long)fkey(d2)) << 32) | (unsigned int)gi;
                if (!(diag && gi == gj) && q < p) p = q;
            }
        {
            unsigned long long o = __shfl_xor(p, 16);
            p = (o < p) ? o : p;
            o = __shfl_xor(p, 32);
            p = (o < p) ? o : p;
        }
        if (quad == 0) atomicMin(&nn[gj], p);
    }
}

// helper: 3-way bf16 split
__device__ __forceinline__ void split3(const float* v, u16x8& h8, u16x8& m8, u16x8& l8) {
#pragma unroll
    for (int j = 0; j < 8; ++j) {
        const float x = v[j];
        const unsigned short h = f2bf(x);
        const float r1 = x - bf2f(h);
        const unsigned short m = f2bf(r1);
        const float r2 = r1 - bf2f(m);
        h8[j] = h; m8[j] = m; l8[j] = f2bf(r2);
    }
}
// helper: 2-way split
__device__ __forceinline__ void split2(const float* v, u16x8& h8, u16x8& l8) {
#pragma unroll
    for (int j = 0; j < 8; ++j) {
        const float x = v[j];
        const unsigned short h = f2bf(x);
        h8[j] = h; l8[j] = f2bf(x - bf2f(h));
    }
}

// ---------------------------------------------------------------- k_p
// P = xs @ W1^T via 3-way-split bf16 MFMA (6 products, gate-safe).
__global__ __launch_bounds__(256) void k_p(const float* __restrict__ xs,
                                           const float* __restrict__ W1,
                                           float* __restrict__ P) {
    __shared__ __align__(16) unsigned short lAh[64 * 32], lAm[64 * 32], lAl[64 * 32];
    __shared__ __align__(16) unsigned short lWh[64 * 32], lWm[64 * 32], lWl[64 * 32];
    const int tid = threadIdx.x, wave = tid >> 6, lane = tid & 63, quad = lane >> 4,
              ln = lane & 15;
    const int i0 = blockIdx.x * 64;
    const int row = tid >> 2, c = tid & 3;
    const int wofs = row * 32 + ((c + (row >> 1)) & 3) * 8;

    f32x4 acc[4];
#pragma unroll
    for (int ns = 0; ns < 4; ++ns) acc[ns] = (f32x4){0.f, 0.f, 0.f, 0.f};

    const int ar = wave * 16 + ln;
    const int aofs = ar * 32 + ((quad + (ar >> 1)) & 3) * 8;
    int bofs[4];
#pragma unroll
    for (int ns = 0; ns < 4; ++ns) {
        const int br = ns * 16 + ln;
        bofs[ns] = br * 32 + ((quad + (br >> 1)) & 3) * 8;
    }

    for (int kt = 0; kt < 16; ++kt) {
        __syncthreads();
        {
            const float* src = xs + (size_t)(i0 + row) * DIM + kt * 32 + c * 8;
            const float4 f0 = *(const float4*)src, f1 = *(const float4*)(src + 4);
            float v[8] = {f0.x, f0.y, f0.z, f0.w, f1.x, f1.y, f1.z, f1.w};
            u16x8 h8, m8, l8;
            split3(v, h8, m8, l8);
            *(u16x8*)(lAh + wofs) = h8;
            *(u16x8*)(lAm + wofs) = m8;
            *(u16x8*)(lAl + wofs) = l8;
        }
        {
            const float* src = W1 + (size_t)row * DIM + kt * 32 + c * 8;
            const float4 f0 = *(const float4*)src, f1 = *(const float4*)(src + 4);
            float v[8] = {f0.x, f0.y, f0.z, f0.w, f1.x, f1.y, f1.z, f1.w};
            u16x8 h8, m8, l8;
            split3(v, h8, m8, l8);
            *(u16x8*)(lWh + wofs) = h8;
            *(u16x8*)(lWm + wofs) = m8;
            *(u16x8*)(lWl + wofs) = l8;
        }
        __syncthreads();
        const bf16x8 ah = *(const bf16x8*)(lAh + aofs);
        const bf16x8 am = *(const bf16x8*)(lAm + aofs);
        const bf16x8 al = *(const bf16x8*)(lAl + aofs);
#pragma unroll
        for (int ns = 0; ns < 4; ++ns) {
            const bf16x8 bh = *(const bf16x8*)(lWh + bofs[ns]);
            const bf16x8 bm = *(const bf16x8*)(lWm + bofs[ns]);
            const bf16x8 bl = *(const bf16x8*)(lWl + bofs[ns]);
            acc[ns] = __builtin_amdgcn_mfma_f32_16x16x32_bf16(ah, bh, acc[ns], 0, 0, 0);
            acc[ns] = __builtin_amdgcn_mfma_f32_16x16x32_bf16(ah, bm, acc[ns], 0, 0, 0);
            acc[ns] = __builtin_amdgcn_mfma_f32_16x16x32_bf16(am, bh, acc[ns], 0, 0, 0);
            acc[ns] = __builtin_amdgcn_mfma_f32_16x16x32_bf16(am, bm, acc[ns], 0, 0, 0);
            acc[ns] = __builtin_amdgcn_mfma_f32_16x16x32_bf16(ah, bl, acc[ns], 0, 0, 0);
            acc[ns] = __builtin_amdgcn_mfma_f32_16x16x32_bf16(al, bh, acc[ns], 0, 0, 0);
        }
    }
#pragma unroll
    for (int ns = 0; ns < 4; ++ns)
#pragma unroll
        for (int v = 0; v < 4; ++v)
            P[(size_t)(i0 + wave * 16 + quad * 4 + v) * 64 + ns * 16 + ln] = acc[ns][v];
}

// ---------------------------------------------------------------- k_tail
__global__ __launch_bounds__(64) void k_tail(const float* __restrict__ P,
                                             const unsigned long long* __restrict__ nn,
                                             const float* __restrict__ b1,
                                             const float* __restrict__ W2,
                                             const float* __restrict__ b2,
                                             const float* __restrict__ W3,
                                             const float* __restrict__ b3,
                                             const float* __restrict__ D1,
                                             const float* __restrict__ d1,
                                             const float* __restrict__ D2,
                                             const float* __restrict__ d2,
                                             float* __restrict__ out_zs,
                                             float* __restrict__ G2) {
    __shared__ float ls[32 * 64];
    const int lane = threadIdx.x;
    const int row = blockIdx.x * 64 + lane;
    const unsigned int nnr = (unsigned int)(nn[row] & 0xFFFFFFFFull) & 8191u;
    const float* pr = P + (size_t)row * 64;
    const float* p0 = P + (size_t)nnr * 64;

    float h1[64], th1[64];
#pragma unroll
    for (int k = 0; k < 64; k += 4) {
        const float4 a = *(const float4*)(pr + k);
        const float4 b = *(const float4*)(p0 + k);
        const float pv[4] = {a.x, a.y, a.z, a.w}, qv[4] = {b.x, b.y, b.z, b.w};
#pragma unroll
        for (int j = 0; j < 4; ++j) {
            const float a1 = qv[j] + b1[k + j];
            h1[k + j] = fmaxf(a1, 0.f);
            th1[k + j] = (a1 > 0.f) ? (pv[j] - qv[j]) : 0.f;
        }
    }
    for (int o = 0; o < 32; o += 2) {
        float a0 = b2[o], u0 = 0.f, a1v = b2[o + 1], u1v = 0.f;
        const float* w0 = W2 + o * 64;
        const float* w1 = W2 + (o + 1) * 64;
#pragma unroll
        for (int k = 0; k < 64; ++k) {
            a0 = fmaf(h1[k], w0[k], a0);
            u0 = fmaf(th1[k], w0[k], u0);
            a1v = fmaf(h1[k], w1[k], a1v);
            u1v = fmaf(th1[k], w1[k], u1v);
        }
        ls[o * 64 + lane] = fmaxf(a0, 0.f) + ((a0 > 0.f) ? u0 : 0.f);
        ls[(o + 1) * 64 + lane] = fmaxf(a1v, 0.f) + ((a1v > 0.f) ? u1v : 0.f);
    }
    float sv[32];
#pragma unroll
    for (int k = 0; k < 32; ++k) sv[k] = ls[k * 64 + lane];
    for (int o = 0; o < 32; o += 2) {
        float z0 = b3[o], z1 = b3[o + 1];
        const float* w0 = W3 + o * 32;
        const float* w1 = W3 + (o + 1) * 32;
#pragma unroll
        for (int k = 0; k < 32; ++k) {
            z0 = fmaf(sv[k], w0[k], z0);
            z1 = fmaf(sv[k], w1[k], z1);
        }
        out_zs[(size_t)row * 32 + o] = z0;
        out_zs[(size_t)row * 32 + o + 1] = z1;
        ls[o * 64 + lane] = z0;
        ls[(o + 1) * 64 + lane] = z1;
    }
    float zv[32];
#pragma unroll
    for (int k = 0; k < 32; ++k) zv[k] = ls[k * 64 + lane];
    for (int o = 0; o < 32; o += 2) {
        float g0 = d1[o], g1v = d1[o + 1];
        const float* w0 = D1 + o * 32;
        const float* w1 = D1 + (o + 1) * 32;
#pragma unroll
        for (int k = 0; k < 32; ++k) {
            g0 = fmaf(zv[k], w0[k], g0);
            g1v = fmaf(zv[k], w1[k], g1v);
        }
        ls[o * 64 + lane] = fmaxf(g0, 0.f);
        ls[(o + 1) * 64 + lane] = fmaxf(g1v, 0.f);
    }
    float gv[32];
#pragma unroll
    for (int k = 0; k < 32; ++k) gv[k] = ls[k * 64 + lane];
    for (int o = 0; o < 64; o += 2) {
        float g0 = d2[o], g1v = d2[o + 1];
        const float* w0 = D2 + o * 32;
        const float* w1 = D2 + (o + 1) * 32;
#pragma unroll
        for (int k = 0; k < 32; ++k) {
            g0 = fmaf(gv[k], w0[k], g0);
            g1v = fmaf(gv[k], w1[k], g1v);
        }
        G2[(size_t)row * 64 + o] = fmaxf(g0, 0.f);
        G2[(size_t)row * 64 + o + 1] = fmaxf(g1v, 0.f);
    }
}

// ---------------------------------------------------------------- k_dec
__global__ __launch_bounds__(256) void k_dec(const float* __restrict__ G2,
                                             const float* __restrict__ D3,
                                             const float* __restrict__ d3,
                                             float* __restrict__ xhat) {
    __shared__ __align__(16) unsigned short lGh[128 * 64], lGl[128 * 64];
    __shared__ __align__(16) unsigned short lDh[128 * 64], lDl[128 * 64];
    const int tid = threadIdx.x, wave = tid >> 6, lane = tid & 63, quad = lane >> 4,
              ln = lane & 15;
    const int i0 = blockIdx.x * 128, nbase = blockIdx.y * 128;
    const int m_off = (wave & 1) * 64, n_off = (wave >> 1) * 64;
#pragma unroll
    for (int r = 0; r < 4; ++r) {
        const int g = r * 256 + tid;
        const int row = g >> 3, cIdx = g & 7, half = cIdx >> 2, cc = cIdx & 3;
        const int wofs = row * 64 + half * 32 + ((cc + (row >> 1)) & 3) * 8;
        {
            const float* src = G2 + (size_t)(i0 + row) * 64 + cIdx * 8;
            const float4 f0 = *(const float4*)src, f1 = *(const float4*)(src + 4);
            float v[8] = {f0.x, f0.y, f0.z, f0.w, f1.x, f1.y, f1.z, f1.w};
            u16x8 h8, l8;
            split2(v, h8, l8);
            *(u16x8*)(lGh + wofs) = h8;
            *(u16x8*)(lGl + wofs) = l8;
        }
        {
            const float* src = D3 + (size_t)(nbase + row) * 64 + cIdx * 8;
            const float4 f0 = *(const float4*)src, f1 = *(const float4*)(src + 4);
            float v[8] = {f0.x, f0.y, f0.z, f0.w, f1.x, f1.y, f1.z, f1.w};
            u16x8 h8, l8;
            split2(v, h8, l8);
            *(u16x8*)(lDh + wofs) = h8;
            *(u16x8*)(lDl + wofs) = l8;
        }
    }
    __syncthreads();
    f32x4 acc[4][4];
#pragma unroll
    for (int a = 0; a < 4; ++a)
#pragma unroll
        for (int c = 0; c < 4; ++c) acc[a][c] = (f32x4){0.f, 0.f, 0.f, 0.f};
#pragma unroll
    for (int kk = 0; kk < 2; ++kk) {
        bf16x8 ah[4], al[4], bh[4], bl[4];
#pragma unroll
        for (int ms = 0; ms < 4; ++ms) {
            const int ar = m_off + ms * 16 + ln;
            const int aofs = ar * 64 + kk * 32 + ((quad + (ar >> 1)) & 3) * 8;
            ah[ms] = *(const bf16x8*)(lGh + aofs);
            al[ms] = *(const bf16x8*)(lGl + aofs);
        }
#pragma unroll
        for (int ns = 0; ns < 4; ++ns) {
            const int br = n_off + ns * 16 + ln;
            const int bofs = br * 64 + kk * 32 + ((quad + (br >> 1)) & 3) * 8;
            bh[ns] = *(const bf16x8*)(lDh + bofs);
            bl[ns] = *(const bf16x8*)(lDl + bofs);
        }
#pragma unroll
        for (int ms = 0; ms < 4; ++ms)
#pragma unroll
            for (int ns = 0; ns < 4; ++ns) {
                acc[ms][ns] = __builtin_amdgcn_mfma_f32_16x16x32_bf16(
                    ah[ms], bh[ns], acc[ms][ns], 0, 0, 0);
                acc[ms][ns] = __builtin_amdgcn_mfma_f32_16x16x32_bf16(
                    ah[ms], bl[ns], acc[ms][ns], 0, 0, 0);
                acc[ms][ns] = __builtin_amdgcn_mfma_f32_16x16x32_bf16(
                    al[ms], bh[ns], acc[ms][ns], 0, 0, 0);
            }
    }
    float d3f[4];
#pragma unroll
    for (int ns = 0; ns < 4; ++ns) d3f[ns] = d3[nbase + n_off + ns * 16 + ln];
#pragma unroll
    for (int ms = 0; ms < 4; ++ms)
#pragma unroll
        for (int ns = 0; ns < 4; ++ns)
#pragma unroll
            for (int v = 0; v < 4; ++v) {
                const int m = m_off + ms * 16 + quad * 4 + v;
                const int n = n_off + ns * 16 + ln;
                xhat[(size_t)(i0 + m) * DIM + nbase + n] = acc[ms][ns][v] + d3f[ns];
            }
}

extern "C" void kernel_launch(void* const* d_in, const int* in_sizes, int n_in,
                              void* d_out, int out_size, void* d_ws, size_t ws_size,
                              hipStream_t stream) {
    const float* xs = (const float*)d_in[0];
    const float* W1 = (const float*)d_in[1];
    const float* b1 = (const float*)d_in[2];
    const float* W2 = (const float*)d_in[3];
    const float* b2 = (const float*)d_in[4];
    const float* W3 = (const float*)d_in[5];
    const float* b3 = (const float*)d_in[6];
    const float* D1 = (const float*)d_in[7];
    const float* d1 = (const float*)d_in[8];
    const float* D2 = (const float*)d_in[9];
    const float* d2 = (const float*)d_in[10];
    const float* D3 = (const float*)d_in[11];
    const float* d3 = (const float*)d_in[12];

    char* ws = (char*)d_ws;
    float* sq = (float*)(ws);
    unsigned long long* nn = (unsigned long long*)(ws + 32768);
    unsigned short* xs_hi = (unsigned short*)(ws + 131072);
    unsigned short* xs_mo = (unsigned short*)(ws + 8519680);
    float* P = (float*)(ws + 8519680);   // overlays xs_mo (dead after k_nn)
    float* G2 = (float*)(ws + 10616832);

    float* xhat = (float*)d_out;
    float* zs = (float*)d_out + (size_t)NROWS * DIM;

    hipLaunchKernelGGL(k_prep, dim3(2048), dim3(256), 0, stream, xs, xs_hi, xs_mo, sq, nn);
    hipLaunchKernelGGL(k_nn, dim3(2112), dim3(256), 0, stream, xs_hi, xs_mo, sq, nn);
    hipLaunchKernelGGL(k_p, dim3(128), dim3(256), 0, stream, xs, W1, P);
    hipLaunchKernelGGL(k_tail, dim3(128), dim3(64), 0, stream, P, nn, b1, W2, b2, W3,
                       b3, D1, d1, D2, d2, zs, G2);
    hipLaunchKernelGGL(k_dec, dim3(64, 4), dim3(256), 0, stream, G2, D3, d3, xhat);
}

// Round 10
// 307.056 us; speedup vs baseline: 1.0909x; 1.0909x over previous
//
#include <hip/hip_runtime.h>
#include <hip/hip_bf16.h>

#define NROWS 8192
#define DIM 512
#define NSLOT 130  // per-row top-2 slots: 66 row-side (33 s x 2 nhalf) + 64 col-side

typedef __attribute__((ext_vector_type(8))) short bf16x8;
typedef __attribute__((ext_vector_type(4))) float f32x4;
typedef __attribute__((ext_vector_type(8))) unsigned short u16x8;

__device__ __forceinline__ float bf2f(unsigned short u) {
    return __uint_as_float(((unsigned int)u) << 16);
}
__device__ __forceinline__ unsigned short f2bf(float f) {
    unsigned int b = __float_as_uint(f);
    return (unsigned short)((b + 0x7FFFu + ((b >> 16) & 1u)) >> 16);
}
// monotone float->uint key: a<b <=> fkey(a)<fkey(b)
__device__ __forceinline__ unsigned int fkey(float f) {
    unsigned int b = __float_as_uint(f);
    return (b & 0x80000000u) ? ~b : (b | 0x80000000u);
}
__device__ __forceinline__ float unfkey(unsigned int u) {
    unsigned int b = (u & 0x80000000u) ? (u ^ 0x80000000u) : ~u;
    return __uint_as_float(b);
}
__device__ __forceinline__ unsigned long long min64(unsigned long long a,
                                                    unsigned long long b) {
    return a < b ? a : b;
}

// ---------------------------------------------------------------- k_prep
// bf16-hi plane + sq[row]. Wave = row.
__global__ __launch_bounds__(256) void k_prep(const float* __restrict__ xs,
                                              unsigned short* __restrict__ hi,
                                              float* __restrict__ sq) {
    const int wave = threadIdx.x >> 6, lane = threadIdx.x & 63;
    const int row = blockIdx.x * 4 + wave;
    const float4* xr = (const float4*)(xs + (size_t)row * DIM);
    const float4 a = xr[2 * lane], b = xr[2 * lane + 1];
    float v[8] = {a.x, a.y, a.z, a.w, b.x, b.y, b.z, b.w};
    u16x8 h;
    float s = 0.f;
#pragma unroll
    for (int i = 0; i < 8; ++i) {
        h[i] = f2bf(v[i]);
        s = fmaf(v[i], v[i], s);
    }
    *(u16x8*)(hi + (size_t)row * DIM + lane * 8) = h;
#pragma unroll
    for (int d = 32; d; d >>= 1) s += __shfl_xor(s, d);
    if (lane == 0) sq[row] = s;
}

// ---------------------------------------------------------------- k_nn
// Pass 1: hi-only distance scores, triangle pair-space, XCD supertile.
// Per (row, 64-j-group) writes TOP-2 packed (fkey(score)<<32|idx) to rowtab
// (race-free indexed slots). score = sq[j] - 2*dot (row-constant dropped).
__global__ __launch_bounds__(256) void k_nn(const unsigned short* __restrict__ xh,
                                            const float* __restrict__ sq,
                                            unsigned long long* __restrict__ rowtab) {
    __shared__ __align__(16) unsigned short lAh[128 * 32];
    __shared__ __align__(16) unsigned short lBh[128 * 32];
    const int tid = threadIdx.x;
    const int wave = tid >> 6, lane = tid & 63, quad = lane >> 4, ln = lane & 15;
    const int b = blockIdx.x;
    const int xcd = b & 7, w = b >> 3;
    const int s = w >> 3, bil = w & 7;
    const int bi = xcd * 8 + bil;
    const int bj = (bi + s) & 63;
    const int i0 = bi * 128, j0 = bj * 128;
    const int m_off = (wave & 1) * 64, n_off = (wave >> 1) * 64;

    // staging (R8-style explicit prefetch + swizzled ds_write), hi plane only
    const int row0 = tid >> 2, c0 = tid & 3;
    const int row1 = 64 + row0;
    const size_t gA0 = (size_t)(i0 + row0) * DIM + c0 * 8;
    const size_t gA1 = (size_t)(i0 + row1) * DIM + c0 * 8;
    const size_t gB0 = (size_t)(j0 + row0) * DIM + c0 * 8;
    const size_t gB1 = (size_t)(j0 + row1) * DIM + c0 * 8;
    const int w0 = row0 * 32 + ((c0 + (row0 >> 1)) & 3) * 8;
    const int w1 = row1 * 32 + ((c0 + (row1 >> 1)) & 3) * 8;

    int aoff[4], boff[4];
#pragma unroll
    for (int ms = 0; ms < 4; ++ms) {
        const int r = m_off + ms * 16 + ln;
        aoff[ms] = r * 32 + ((quad + (r >> 1)) & 3) * 8;
    }
#pragma unroll
    for (int ns = 0; ns < 4; ++ns) {
        const int r = n_off + ns * 16 + ln;
        boff[ns] = r * 32 + ((quad + (r >> 1)) & 3) * 8;
    }

    f32x4 acc[4][4];
#pragma unroll
    for (int a = 0; a < 4; ++a)
#pragma unroll
        for (int c = 0; c < 4; ++c) acc[a][c] = (f32x4){0.f, 0.f, 0.f, 0.f};

    uint4 vA0 = *(const uint4*)(xh + gA0), vA1 = *(const uint4*)(xh + gA1);
    uint4 vB0 = *(const uint4*)(xh + gB0), vB1 = *(const uint4*)(xh + gB1);

    for (int kt = 0; kt < 16; ++kt) {
        __syncthreads();
        *(uint4*)(lAh + w0) = vA0; *(uint4*)(lAh + w1) = vA1;
        *(uint4*)(lBh + w0) = vB0; *(uint4*)(lBh + w1) = vB1;
        if (kt < 15) {
            const size_t ko = (size_t)(kt + 1) * 32;
            vA0 = *(const uint4*)(xh + gA0 + ko); vA1 = *(const uint4*)(xh + gA1 + ko);
            vB0 = *(const uint4*)(xh + gB0 + ko); vB1 = *(const uint4*)(xh + gB1 + ko);
        }
        __syncthreads();
        bf16x8 ah[4], bh[4];
#pragma unroll
        for (int ms = 0; ms < 4; ++ms) ah[ms] = *(const bf16x8*)(lAh + aoff[ms]);
#pragma unroll
        for (int ns = 0; ns < 4; ++ns) bh[ns] = *(const bf16x8*)(lBh + boff[ns]);
#pragma unroll
        for (int ms = 0; ms < 4; ++ms)
#pragma unroll
            for (int ns = 0; ns < 4; ++ns)
                acc[ms][ns] = __builtin_amdgcn_mfma_f32_16x16x32_bf16(
                    ah[ms], bh[ns], acc[ms][ns], 0, 0, 0);
    }

    // ---- epilogue: top-2 per group, race-free slot writes ----
    const bool diag = (i0 == j0);
    float sqj[4];
#pragma unroll
    for (int ns = 0; ns < 4; ++ns) sqj[ns] = sq[j0 + n_off + ns * 16 + ln];
    float sqi[4][4];
#pragma unroll
    for (int ms = 0; ms < 4; ++ms)
#pragma unroll
        for (int v = 0; v < 4; ++v)
            sqi[ms][v] = sq[i0 + m_off + ms * 16 + quad * 4 + v];

    // row-side: per i-row, top-2 over this wave's 64 j's
#pragma unroll
    for (int ms = 0; ms < 4; ++ms)
#pragma unroll
        for (int v = 0; v < 4; ++v) {
            const int gi = i0 + m_off + ms * 16 + quad * 4 + v;
            unsigned long long pk[4];
#pragma unroll
            for (int ns = 0; ns < 4; ++ns) {
                const int gj = j0 + n_off + ns * 16 + ln;
                float d2 = fmaf(-2.f, acc[ms][ns][v], sqj[ns]);
                if (diag && gj == gi) d2 = __builtin_inff();
                pk[ns] = (((unsigned long long)fkey(d2)) << 32) | (unsigned int)gj;
            }
            // min1
            unsigned long long m1 = min64(min64(pk[0], pk[1]), min64(pk[2], pk[3]));
#pragma unroll
            for (int d = 1; d < 16; d <<= 1) m1 = min64(m1, __shfl_xor(m1, d));
            // min2: exclude m1 (indices distinct -> unique), reduce again
            unsigned long long m2 = ~0ull;
#pragma unroll
            for (int ns = 0; ns < 4; ++ns)
                m2 = min64(m2, pk[ns] == m1 ? ~0ull : pk[ns]);
#pragma unroll
            for (int d = 1; d < 16; d <<= 1) m2 = min64(m2, __shfl_xor(m2, d));
            if (ln == 0) {
                const size_t base =
                    ((size_t)gi * NSLOT + (s * 2 + (wave >> 1))) * 2;
                rowtab[base] = m1;
                rowtab[base + 1] = m2;
            }
        }
    // col-side: per j-col, top-2 over this wave's 64 i's (skip diag s=0)
    if (s > 0) {
#pragma unroll
        for (int ns = 0; ns < 4; ++ns) {
            const int gj = j0 + n_off + ns * 16 + ln;
            unsigned long long pk[16];
#pragma unroll
            for (int ms = 0; ms < 4; ++ms)
#pragma unroll
                for (int v = 0; v < 4; ++v) {
                    const int gi = i0 + m_off + ms * 16 + quad * 4 + v;
                    const float d2 = fmaf(-2.f, acc[ms][ns][v], sqi[ms][v]);
                    pk[ms * 4 + v] =
                        (((unsigned long long)fkey(d2)) << 32) | (unsigned int)gi;
                }
            unsigned long long m1 = pk[0];
#pragma unroll
            for (int t = 1; t < 16; ++t) m1 = min64(m1, pk[t]);
            m1 = min64(m1, __shfl_xor(m1, 16));
            m1 = min64(m1, __shfl_xor(m1, 32));
            unsigned long long m2 = ~0ull;
#pragma unroll
            for (int t = 0; t < 16; ++t)
                m2 = min64(m2, pk[t] == m1 ? ~0ull : pk[t]);
            m2 = min64(m2, __shfl_xor(m2, 16));
            m2 = min64(m2, __shfl_xor(m2, 32));
            if (quad == 0) {
                const size_t base =
                    ((size_t)gj * NSLOT + (66 + (s - 1) * 2 + (wave & 1))) * 2;
                rowtab[base] = m1;
                rowtab[base + 1] = m2;
            }
        }
    }
}

// ---------------------------------------------------------------- k_refine
// Wave per row: global min over 260 slot entries, candidates within M=2.0,
// exact fp32 np-style d2 (sq[i]+sq[j]-2 dot) for candidates, lexicographic min.
__global__ __launch_bounds__(256) void k_refine(const unsigned long long* __restrict__ rowtab,
                                                const float* __restrict__ xs,
                                                const float* __restrict__ sq,
                                                unsigned long long* __restrict__ nn) {
    __shared__ unsigned long long clist[4][NSLOT * 2];
    __shared__ int ccnt[4];
    const int wave = threadIdx.x >> 6, lane = threadIdx.x & 63;
    const int row = blockIdx.x * 4 + wave;
    if (lane == 0) ccnt[wave] = 0;
    __syncthreads();

    unsigned long long vals[6];
    int nv = 0;
    unsigned long long best = ~0ull;
    for (int i = lane; i < NSLOT * 2; i += 64) {
        const unsigned long long v = rowtab[(size_t)row * NSLOT * 2 + i];
        vals[nv++] = v;
        best = min64(best, v);
    }
#pragma unroll
    for (int d = 1; d < 64; d <<= 1) best = min64(best, __shfl_xor(best, d));

    const float dmin = unfkey((unsigned int)(best >> 32));
    const unsigned int tkey = fkey(dmin + 2.0f);  // M = 2.0 (~18 sigma)
    for (int k = 0; k < nv; ++k)
        if ((unsigned int)(vals[k] >> 32) < tkey) {
            const int p = atomicAdd(&ccnt[wave], 1);
            clist[wave][p] = vals[k];
        }
    __syncthreads();
    const int cnt = ccnt[wave];

    const float4* xi = (const float4*)(xs + (size_t)row * DIM);
    const float4 x0 = xi[2 * lane], x1 = xi[2 * lane + 1];
    const float sqi = sq[row];
    unsigned long long bestf = ~0ull;
    for (int c = 0; c < cnt; ++c) {
        const unsigned int j = (unsigned int)(clist[wave][c] & 0xFFFFFFFFull);
        const float4* xj = (const float4*)(xs + (size_t)j * DIM);
        const float4 y0 = xj[2 * lane], y1 = xj[2 * lane + 1];
        float dot = 0.f;
        dot = fmaf(x0.x, y0.x, dot); dot = fmaf(x0.y, y0.y, dot);
        dot = fmaf(x0.z, y0.z, dot); dot = fmaf(x0.w, y0.w, dot);
        dot = fmaf(x1.x, y1.x, dot); dot = fmaf(x1.y, y1.y, dot);
        dot = fmaf(x1.z, y1.z, dot); dot = fmaf(x1.w, y1.w, dot);
#pragma unroll
        for (int d = 1; d < 64; d <<= 1) dot += __shfl_xor(dot, d);
        const float d2 = sqi + sq[j] - 2.f * dot;
        const unsigned long long pk = (((unsigned long long)fkey(d2)) << 32) | j;
        bestf = min64(bestf, pk);
    }
    if (lane == 0) nn[row] = bestf;
}

// helpers for tail GEMMs
__device__ __forceinline__ void split3(const float* v, u16x8& h8, u16x8& m8, u16x8& l8) {
#pragma unroll
    for (int j = 0; j < 8; ++j) {
        const float x = v[j];
        const unsigned short h = f2bf(x);
        const float r1 = x - bf2f(h);
        const unsigned short m = f2bf(r1);
        const float r2 = r1 - bf2f(m);
        h8[j] = h; m8[j] = m; l8[j] = f2bf(r2);
    }
}
__device__ __forceinline__ void split2(const float* v, u16x8& h8, u16x8& l8) {
#pragma unroll
    for (int j = 0; j < 8; ++j) {
        const float x = v[j];
        const unsigned short h = f2bf(x);
        h8[j] = h; l8[j] = f2bf(x - bf2f(h));
    }
}

// ---------------------------------------------------------------- k_p  (unchanged R8)
__global__ __launch_bounds__(256) void k_p(const float* __restrict__ xs,
                                           const float* __restrict__ W1,
                                           float* __restrict__ P) {
    __shared__ __align__(16) unsigned short lAh[64 * 32], lAm[64 * 32], lAl[64 * 32];
    __shared__ __align__(16) unsigned short lWh[64 * 32], lWm[64 * 32], lWl[64 * 32];
    const int tid = threadIdx.x, wave = tid >> 6, lane = tid & 63, quad = lane >> 4,
              ln = lane & 15;
    const int i0 = blockIdx.x * 64;
    const int row = tid >> 2, c = tid & 3;
    const int wofs = row * 32 + ((c + (row >> 1)) & 3) * 8;

    f32x4 acc[4];
#pragma unroll
    for (int ns = 0; ns < 4; ++ns) acc[ns] = (f32x4){0.f, 0.f, 0.f, 0.f};

    const int ar = wave * 16 + ln;
    const int aofs = ar * 32 + ((quad + (ar >> 1)) & 3) * 8;
    int bofs[4];
#pragma unroll
    for (int ns = 0; ns < 4; ++ns) {
        const int br = ns * 16 + ln;
        bofs[ns] = br * 32 + ((quad + (br >> 1)) & 3) * 8;
    }

    for (int kt = 0; kt < 16; ++kt) {
        __syncthreads();
        {
            const float* src = xs + (size_t)(i0 + row) * DIM + kt * 32 + c * 8;
            const float4 f0 = *(const float4*)src, f1 = *(const float4*)(src + 4);
            float v[8] = {f0.x, f0.y, f0.z, f0.w, f1.x, f1.y, f1.z, f1.w};
            u16x8 h8, m8, l8;
            split3(v, h8, m8, l8);
            *(u16x8*)(lAh + wofs) = h8;
            *(u16x8*)(lAm + wofs) = m8;
            *(u16x8*)(lAl + wofs) = l8;
        }
        {
            const float* src = W1 + (size_t)row * DIM + kt * 32 + c * 8;
            const float4 f0 = *(const float4*)src, f1 = *(const float4*)(src + 4);
            float v[8] = {f0.x, f0.y, f0.z, f0.w, f1.x, f1.y, f1.z, f1.w};
            u16x8 h8, m8, l8;
            split3(v, h8, m8, l8);
            *(u16x8*)(lWh + wofs) = h8;
            *(u16x8*)(lWm + wofs) = m8;
            *(u16x8*)(lWl + wofs) = l8;
        }
        __syncthreads();
        const bf16x8 ah = *(const bf16x8*)(lAh + aofs);
        const bf16x8 am = *(const bf16x8*)(lAm + aofs);
        const bf16x8 al = *(const bf16x8*)(lAl + aofs);
#pragma unroll
        for (int ns = 0; ns < 4; ++ns) {
            const bf16x8 bh = *(const bf16x8*)(lWh + bofs[ns]);
            const bf16x8 bm = *(const bf16x8*)(lWm + bofs[ns]);
            const bf16x8 bl = *(const bf16x8*)(lWl + bofs[ns]);
            acc[ns] = __builtin_amdgcn_mfma_f32_16x16x32_bf16(ah, bh, acc[ns], 0, 0, 0);
            acc[ns] = __builtin_amdgcn_mfma_f32_16x16x32_bf16(ah, bm, acc[ns], 0, 0, 0);
            acc[ns] = __builtin_amdgcn_mfma_f32_16x16x32_bf16(am, bh, acc[ns], 0, 0, 0);
            acc[ns] = __builtin_amdgcn_mfma_f32_16x16x32_bf16(am, bm, acc[ns], 0, 0, 0);
            acc[ns] = __builtin_amdgcn_mfma_f32_16x16x32_bf16(ah, bl, acc[ns], 0, 0, 0);
            acc[ns] = __builtin_amdgcn_mfma_f32_16x16x32_bf16(al, bh, acc[ns], 0, 0, 0);
        }
    }
#pragma unroll
    for (int ns = 0; ns < 4; ++ns)
#pragma unroll
        for (int v = 0; v < 4; ++v)
            P[(size_t)(i0 + wave * 16 + quad * 4 + v) * 64 + ns * 16 + ln] = acc[ns][v];
}

// ---------------------------------------------------------------- k_tail  (unchanged R8)
__global__ __launch_bounds__(64) void k_tail(const float* __restrict__ P,
                                             const unsigned long long* __restrict__ nn,
                                             const float* __restrict__ b1,
                                             const float* __restrict__ W2,
                                             const float* __restrict__ b2,
                                             const float* __restrict__ W3,
                                             const float* __restrict__ b3,
                                             const float* __restrict__ D1,
                                             const float* __restrict__ d1,
                                             const float* __restrict__ D2,
                                             const float* __restrict__ d2,
                                             float* __restrict__ out_zs,
                                             float* __restrict__ G2) {
    __shared__ float ls[32 * 64];
    const int lane = threadIdx.x;
    const int row = blockIdx.x * 64 + lane;
    const unsigned int nnr = (unsigned int)(nn[row] & 0xFFFFFFFFull) & 8191u;
    const float* pr = P + (size_t)row * 64;
    const float* p0 = P + (size_t)nnr * 64;

    float h1[64], th1[64];
#pragma unroll
    for (int k = 0; k < 64; k += 4) {
        const float4 a = *(const float4*)(pr + k);
        const float4 b = *(const float4*)(p0 + k);
        const float pv[4] = {a.x, a.y, a.z, a.w}, qv[4] = {b.x, b.y, b.z, b.w};
#pragma unroll
        for (int j = 0; j < 4; ++j) {
            const float a1 = qv[j] + b1[k + j];
            h1[k + j] = fmaxf(a1, 0.f);
            th1[k + j] = (a1 > 0.f) ? (pv[j] - qv[j]) : 0.f;
        }
    }
    for (int o = 0; o < 32; o += 2) {
        float a0 = b2[o], u0 = 0.f, a1v = b2[o + 1], u1v = 0.f;
        const float* w0 = W2 + o * 64;
        const float* w1 = W2 + (o + 1) * 64;
#pragma unroll
        for (int k = 0; k < 64; ++k) {
            a0 = fmaf(h1[k], w0[k], a0);
            u0 = fmaf(th1[k], w0[k], u0);
            a1v = fmaf(h1[k], w1[k], a1v);
            u1v = fmaf(th1[k], w1[k], u1v);
        }
        ls[o * 64 + lane] = fmaxf(a0, 0.f) + ((a0 > 0.f) ? u0 : 0.f);
        ls[(o + 1) * 64 + lane] = fmaxf(a1v, 0.f) + ((a1v > 0.f) ? u1v : 0.f);
    }
    float sv[32];
#pragma unroll
    for (int k = 0; k < 32; ++k) sv[k] = ls[k * 64 + lane];
    for (int o = 0; o < 32; o += 2) {
        float z0 = b3[o], z1 = b3[o + 1];
        const float* w0 = W3 + o * 32;
        const float* w1 = W3 + (o + 1) * 32;
#pragma unroll
        for (int k = 0; k < 32; ++k) {
            z0 = fmaf(sv[k], w0[k], z0);
            z1 = fmaf(sv[k], w1[k], z1);
        }
        out_zs[(size_t)row * 32 + o] = z0;
        out_zs[(size_t)row * 32 + o + 1] = z1;
        ls[o * 64 + lane] = z0;
        ls[(o + 1) * 64 + lane] = z1;
    }
    float zv[32];
#pragma unroll
    for (int k = 0; k < 32; ++k) zv[k] = ls[k * 64 + lane];
    for (int o = 0; o < 32; o += 2) {
        float g0 = d1[o], g1v = d1[o + 1];
        const float* w0 = D1 + o * 32;
        const float* w1 = D1 + (o + 1) * 32;
#pragma unroll
        for (int k = 0; k < 32; ++k) {
            g0 = fmaf(zv[k], w0[k], g0);
            g1v = fmaf(zv[k], w1[k], g1v);
        }
        ls[o * 64 + lane] = fmaxf(g0, 0.f);
        ls[(o + 1) * 64 + lane] = fmaxf(g1v, 0.f);
    }
    float gv[32];
#pragma unroll
    for (int k = 0; k < 32; ++k) gv[k] = ls[k * 64 + lane];
    for (int o = 0; o < 64; o += 2) {
        float g0 = d2[o], g1v = d2[o + 1];
        const float* w0 = D2 + o * 32;
        const float* w1 = D2 + (o + 1) * 32;
#pragma unroll
        for (int k = 0; k < 32; ++k) {
            g0 = fmaf(gv[k], w0[k], g0);
            g1v = fmaf(gv[k], w1[k], g1v);
        }
        G2[(size_t)row * 64 + o] = fmaxf(g0, 0.f);
        G2[(size_t)row * 64 + o + 1] = fmaxf(g1v, 0.f);
    }
}

// ---------------------------------------------------------------- k_dec  (unchanged R8)
__global__ __launch_bounds__(256) void k_dec(const float* __restrict__ G2,
                                             const float* __restrict__ D3,
                                             const float* __restrict__ d3,
                                             float* __restrict__ xhat) {
    __shared__ __align__(16) unsigned short lGh[128 * 64], lGl[128 * 64];
    __shared__ __align__(16) unsigned short lDh[128 * 64], lDl[128 * 64];
    const int tid = threadIdx.x, wave = tid >> 6, lane = tid & 63, quad = lane >> 4,
              ln = lane & 15;
    const int i0 = blockIdx.x * 128, nbase = blockIdx.y * 128;
    const int m_off = (wave & 1) * 64, n_off = (wave >> 1) * 64;
#pragma unroll
    for (int r = 0; r < 4; ++r) {
        const int g = r * 256 + tid;
        const int row = g >> 3, cIdx = g & 7, half = cIdx >> 2, cc = cIdx & 3;
        const int wofs = row * 64 + half * 32 + ((cc + (row >> 1)) & 3) * 8;
        {
            const float* src = G2 + (size_t)(i0 + row) * 64 + cIdx * 8;
            const float4 f0 = *(const float4*)src, f1 = *(const float4*)(src + 4);
            float v[8] = {f0.x, f0.y, f0.z, f0.w, f1.x, f1.y, f1.z, f1.w};
            u16x8 h8, l8;
            split2(v, h8, l8);
            *(u16x8*)(lGh + wofs) = h8;
            *(u16x8*)(lGl + wofs) = l8;
        }
        {
            const float* src = D3 + (size_t)(nbase + row) * 64 + cIdx * 8;
            const float4 f0 = *(const float4*)src, f1 = *(const float4*)(src + 4);
            float v[8] = {f0.x, f0.y, f0.z, f0.w, f1.x, f1.y, f1.z, f1.w};
            u16x8 h8, l8;
            split2(v, h8, l8);
            *(u16x8*)(lDh + wofs) = h8;
            *(u16x8*)(lDl + wofs) = l8;
        }
    }
    __syncthreads();
    f32x4 acc[4][4];
#pragma unroll
    for (int a = 0; a < 4; ++a)
#pragma unroll
        for (int c = 0; c < 4; ++c) acc[a][c] = (f32x4){0.f, 0.f, 0.f, 0.f};
#pragma unroll
    for (int kk = 0; kk < 2; ++kk) {
        bf16x8 ah[4], al[4], bh[4], bl[4];
#pragma unroll
        for (int ms = 0; ms < 4; ++ms) {
            const int ar = m_off + ms * 16 + ln;
            const int aofs = ar * 64 + kk * 32 + ((quad + (ar >> 1)) & 3) * 8;
            ah[ms] = *(const bf16x8*)(lGh + aofs);
            al[ms] = *(const bf16x8*)(lGl + aofs);
        }
#pragma unroll
        for (int ns = 0; ns < 4; ++ns) {
            const int br = n_off + ns * 16 + ln;
            const int bofs = br * 64 + kk * 32 + ((quad + (br >> 1)) & 3) * 8;
            bh[ns] = *(const bf16x8*)(lDh + bofs);
            bl[ns] = *(const bf16x8*)(lDl + bofs);
        }
#pragma unroll
        for (int ms = 0; ms < 4; ++ms)
#pragma unroll
            for (int ns = 0; ns < 4; ++ns) {
                acc[ms][ns] = __builtin_amdgcn_mfma_f32_16x16x32_bf16(
                    ah[ms], bh[ns], acc[ms][ns], 0, 0, 0);
                acc[ms][ns] = __builtin_amdgcn_mfma_f32_16x16x32_bf16(
                    ah[ms], bl[ns], acc[ms][ns], 0, 0, 0);
                acc[ms][ns] = __builtin_amdgcn_mfma_f32_16x16x32_bf16(
                    al[ms], bh[ns], acc[ms][ns], 0, 0, 0);
            }
    }
    float d3f[4];
#pragma unroll
    for (int ns = 0; ns < 4; ++ns) d3f[ns] = d3[nbase + n_off + ns * 16 + ln];
#pragma unroll
    for (int ms = 0; ms < 4; ++ms)
#pragma unroll
        for (int ns = 0; ns < 4; ++ns)
#pragma unroll
            for (int v = 0; v < 4; ++v) {
                const int m = m_off + ms * 16 + quad * 4 + v;
                const int n = n_off + ns * 16 + ln;
                xhat[(size_t)(i0 + m) * DIM + nbase + n] = acc[ms][ns][v] + d3f[ns];
            }
}

extern "C" void kernel_launch(void* const* d_in, const int* in_sizes, int n_in,
                              void* d_out, int out_size, void* d_ws, size_t ws_size,
                              hipStream_t stream) {
    const float* xs = (const float*)d_in[0];
    const float* W1 = (const float*)d_in[1];
    const float* b1 = (const float*)d_in[2];
    const float* W2 = (const float*)d_in[3];
    const float* b2 = (const float*)d_in[4];
    const float* W3 = (const float*)d_in[5];
    const float* b3 = (const float*)d_in[6];
    const float* D1 = (const float*)d_in[7];
    const float* d1 = (const float*)d_in[8];
    const float* D2 = (const float*)d_in[9];
    const float* d2 = (const float*)d_in[10];
    const float* D3 = (const float*)d_in[11];
    const float* d3 = (const float*)d_in[12];

    // ws (12.7 MB, proven-safe layout): sq | nn | xs_hi | P | G2
    char* ws = (char*)d_ws;
    float* sq = (float*)(ws);                                     // 32 KB
    unsigned long long* nn = (unsigned long long*)(ws + 32768);   // 64 KB
    unsigned short* xs_hi = (unsigned short*)(ws + 131072);       // 8 MB
    float* P = (float*)(ws + 8519680);                            // 2 MB
    float* G2 = (float*)(ws + 10616832);                          // 2 MB

    float* xhat = (float*)d_out;
    float* zs = (float*)d_out + (size_t)NROWS * DIM;
    // rowtab scratch lives in d_out (17.04 MB needed <= 17.83 MB available);
    // dead before k_tail/k_dec overwrite d_out with final values.
    unsigned long long* rowtab = (unsigned long long*)d_out;

    hipLaunchKernelGGL(k_prep, dim3(2048), dim3(256), 0, stream, xs, xs_hi, sq);
    hipLaunchKernelGGL(k_nn, dim3(2112), dim3(256), 0, stream, xs_hi, sq, rowtab);
    hipLaunchKernelGGL(k_refine, dim3(2048), dim3(256), 0, stream, rowtab, xs, sq, nn);
    hipLaunchKernelGGL(k_p, dim3(128), dim3(256), 0, stream, xs, W1, P);
    hipLaunchKernelGGL(k_tail, dim3(128), dim3(64), 0, stream, P, nn, b1, W2, b2, W3,
                       b3, D1, d1, D2, d2, zs, G2);
    hipLaunchKernelGGL(k_dec, dim3(64, 4), dim3(256), 0, stream, G2, D3, d3, xhat);
}

// Round 11
// 298.078 us; speedup vs baseline: 1.1237x; 1.0301x over previous
//
#include <hip/hip_runtime.h>
#include <hip/hip_bf16.h>

#define NROWS 8192
#define DIM 512
#define NSLOT 130  // per-row top-2 slots: 66 row-side + 64 col-side
#define KMASK 0xFFFFE000u  // top-19 key bits; low 13 = index

typedef __attribute__((ext_vector_type(8))) short bf16x8;
typedef __attribute__((ext_vector_type(4))) float f32x4;
typedef __attribute__((ext_vector_type(8))) unsigned short u16x8;

__device__ __forceinline__ float bf2f(unsigned short u) {
    return __uint_as_float(((unsigned int)u) << 16);
}
__device__ __forceinline__ unsigned short f2bf(float f) {
    unsigned int b = __float_as_uint(f);
    return (unsigned short)((b + 0x7FFFu + ((b >> 16) & 1u)) >> 16);
}
// monotone float->uint key: a<b <=> fkey(a)<fkey(b)
__device__ __forceinline__ unsigned int fkey(float f) {
    unsigned int b = __float_as_uint(f);
    return (b & 0x80000000u) ? ~b : (b | 0x80000000u);
}
__device__ __forceinline__ float unfkey(unsigned int u) {
    unsigned int b = (u & 0x80000000u) ? (u ^ 0x80000000u) : ~u;
    return __uint_as_float(b);
}
__device__ __forceinline__ unsigned int minu(unsigned int a, unsigned int b) {
    return a < b ? a : b;
}
__device__ __forceinline__ unsigned long long min64(unsigned long long a,
                                                    unsigned long long b) {
    return a < b ? a : b;
}

// ---------------------------------------------------------------- k_prep
__global__ __launch_bounds__(256) void k_prep(const float* __restrict__ xs,
                                              unsigned short* __restrict__ hi,
                                              float* __restrict__ sq) {
    const int wave = threadIdx.x >> 6, lane = threadIdx.x & 63;
    const int row = blockIdx.x * 4 + wave;
    const float4* xr = (const float4*)(xs + (size_t)row * DIM);
    const float4 a = xr[2 * lane], b = xr[2 * lane + 1];
    float v[8] = {a.x, a.y, a.z, a.w, b.x, b.y, b.z, b.w};
    u16x8 h;
    float s = 0.f;
#pragma unroll
    for (int i = 0; i < 8; ++i) {
        h[i] = f2bf(v[i]);
        s = fmaf(v[i], v[i], s);
    }
    *(u16x8*)(hi + (size_t)row * DIM + lane * 8) = h;
#pragma unroll
    for (int d = 32; d; d >>= 1) s += __shfl_xor(s, d);
    if (lane == 0) sq[row] = s;
}

// ---------------------------------------------------------------- k_nn
// Pass 1: hi-only scores. DMA double-buffered staging (issue kt+1 after the
// barrier, overlap with MFMA on kt), u32-packed top-2 epilogue.
__global__ __launch_bounds__(256) void k_nn(const unsigned short* __restrict__ xh,
                                            const float* __restrict__ sq,
                                            unsigned int* __restrict__ rowtab) {
    __shared__ __align__(16) unsigned short lA[2 * 128 * 32];
    __shared__ __align__(16) unsigned short lB[2 * 128 * 32];
    const int tid = threadIdx.x;
    const int wave = tid >> 6, lane = tid & 63, quad = lane >> 4, ln = lane & 15;
    const int b = blockIdx.x;
    const int xcd = b & 7, w = b >> 3;
    const int s = w >> 3, bil = w & 7;
    const int bi = xcd * 8 + bil;
    const int bj = (bi + s) & 63;
    const int i0 = bi * 128, j0 = bj * 128;
    const int m_off = (wave & 1) * 64, n_off = (wave >> 1) * 64;

    // DMA staging: waves 0,1 stage lA halves; waves 2,3 stage lB halves.
    // Lane mapping (R9-proven): linear landing == conflict-free swizzle.
    const int rl = lane >> 2;
    const int cc = ((lane & 3) - (rl >> 1)) & 3;
    unsigned short* lbase = ((wave < 2) ? lA : lB) + (wave & 1) * 2048;
    const int trow = ((wave < 2) ? i0 : j0) + (wave & 1) * 64;
    const unsigned short* gp = xh + (size_t)(trow + rl) * DIM + cc * 8;

    int aoff[4], boff[4];
#pragma unroll
    for (int ms = 0; ms < 4; ++ms) {
        const int r = m_off + ms * 16 + ln;
        aoff[ms] = r * 32 + ((quad + (r >> 1)) & 3) * 8;
    }
#pragma unroll
    for (int ns = 0; ns < 4; ++ns) {
        const int r = n_off + ns * 16 + ln;
        boff[ns] = r * 32 + ((quad + (r >> 1)) & 3) * 8;
    }

    f32x4 acc[4][4];
#pragma unroll
    for (int a = 0; a < 4; ++a)
#pragma unroll
        for (int c = 0; c < 4; ++c) acc[a][c] = (f32x4){0.f, 0.f, 0.f, 0.f};

    // preload kt=0 into buf0
#pragma unroll
    for (int st = 0; st < 4; ++st)
        __builtin_amdgcn_global_load_lds(
            (const __attribute__((address_space(1))) void*)(gp + (size_t)(st * 16) * DIM),
            (__attribute__((address_space(3))) void*)(lbase + st * 512), 16, 0, 0);

    for (int kt = 0; kt < 16; ++kt) {
        __syncthreads();  // drains the DMA filling buf[kt&1]; prior reads done
        const int cur = (kt & 1) * 4096;
        if (kt < 15) {
            const int nxt = ((kt + 1) & 1) * 4096;
            const unsigned short* g = gp + (kt + 1) * 32;
#pragma unroll
            for (int st = 0; st < 4; ++st)
                __builtin_amdgcn_global_load_lds(
                    (const __attribute__((address_space(1))) void*)(g + (size_t)(st * 16) * DIM),
                    (__attribute__((address_space(3))) void*)(lbase + nxt + st * 512),
                    16, 0, 0);
        }
        bf16x8 ah[4], bh[4];
#pragma unroll
        for (int ms = 0; ms < 4; ++ms)
            ah[ms] = *(const bf16x8*)(lA + cur + aoff[ms]);
#pragma unroll
        for (int ns = 0; ns < 4; ++ns)
            bh[ns] = *(const bf16x8*)(lB + cur + boff[ns]);
#pragma unroll
        for (int ms = 0; ms < 4; ++ms)
#pragma unroll
            for (int ns = 0; ns < 4; ++ns)
                acc[ms][ns] = __builtin_amdgcn_mfma_f32_16x16x32_bf16(
                    ah[ms], bh[ns], acc[ms][ns], 0, 0, 0);
    }

    // ---- epilogue: u32-packed top-2 per group ----
    const bool diag = (i0 == j0);
    float sqj[4];
#pragma unroll
    for (int ns = 0; ns < 4; ++ns) sqj[ns] = sq[j0 + n_off + ns * 16 + ln];
    float sqi[4][4];
#pragma unroll
    for (int ms = 0; ms < 4; ++ms)
#pragma unroll
        for (int v = 0; v < 4; ++v)
            sqi[ms][v] = sq[i0 + m_off + ms * 16 + quad * 4 + v];

    // row-side
#pragma unroll
    for (int ms = 0; ms < 4; ++ms)
#pragma unroll
        for (int v = 0; v < 4; ++v) {
            const int gi = i0 + m_off + ms * 16 + quad * 4 + v;
            unsigned int pk[4];
#pragma unroll
            for (int ns = 0; ns < 4; ++ns) {
                const int gj = j0 + n_off + ns * 16 + ln;
                float d2 = fmaf(-2.f, acc[ms][ns][v], sqj[ns]);
                if (diag && gj == gi) d2 = __builtin_inff();
                pk[ns] = (fkey(d2) & KMASK) | (unsigned int)gj;
            }
            unsigned int m1 = minu(minu(pk[0], pk[1]), minu(pk[2], pk[3]));
#pragma unroll
            for (int d = 1; d < 16; d <<= 1) m1 = minu(m1, __shfl_xor(m1, d));
            unsigned int m2 = 0xFFFFFFFFu;
#pragma unroll
            for (int ns = 0; ns < 4; ++ns)
                m2 = minu(m2, pk[ns] == m1 ? 0xFFFFFFFFu : pk[ns]);
#pragma unroll
            for (int d = 1; d < 16; d <<= 1) m2 = minu(m2, __shfl_xor(m2, d));
            if (ln == 0) {
                const size_t base = ((size_t)gi * NSLOT + (s * 2 + (wave >> 1))) * 2;
                rowtab[base] = m1;
                rowtab[base + 1] = m2;
            }
        }
    // col-side (skip diag block)
    if (s > 0) {
#pragma unroll
        for (int ns = 0; ns < 4; ++ns) {
            const int gj = j0 + n_off + ns * 16 + ln;
            unsigned int pk[16];
#pragma unroll
            for (int ms = 0; ms < 4; ++ms)
#pragma unroll
                for (int v = 0; v < 4; ++v) {
                    const int gi = i0 + m_off + ms * 16 + quad * 4 + v;
                    const float d2 = fmaf(-2.f, acc[ms][ns][v], sqi[ms][v]);
                    pk[ms * 4 + v] = (fkey(d2) & KMASK) | (unsigned int)gi;
                }
            unsigned int m1 = pk[0];
#pragma unroll
            for (int t = 1; t < 16; ++t) m1 = minu(m1, pk[t]);
            m1 = minu(m1, __shfl_xor(m1, 16));
            m1 = minu(m1, __shfl_xor(m1, 32));
            unsigned int m2 = 0xFFFFFFFFu;
#pragma unroll
            for (int t = 0; t < 16; ++t)
                m2 = minu(m2, pk[t] == m1 ? 0xFFFFFFFFu : pk[t]);
            m2 = minu(m2, __shfl_xor(m2, 16));
            m2 = minu(m2, __shfl_xor(m2, 32));
            if (quad == 0) {
                const size_t base =
                    ((size_t)gj * NSLOT + (66 + (s - 1) * 2 + (wave & 1))) * 2;
                rowtab[base] = m1;
                rowtab[base + 1] = m2;
            }
        }
    }
}

// ---------------------------------------------------------------- k_refine
// Wave per row: global min over 260 u32 entries, candidates within margin 4.0
// (noise + quantization), exact fp32 np-style d2 recompute, lexicographic min.
__global__ __launch_bounds__(256) void k_refine(const unsigned int* __restrict__ rowtab,
                                                const float* __restrict__ xs,
                                                const float* __restrict__ sq,
                                                unsigned long long* __restrict__ nn) {
    __shared__ unsigned int clist[4][64];
    __shared__ int ccnt[4];
    const int wave = threadIdx.x >> 6, lane = threadIdx.x & 63;
    const int row = blockIdx.x * 4 + wave;
    if (lane == 0) ccnt[wave] = 0;
    __syncthreads();

    unsigned int vals[5];
    int nv = 0;
    unsigned int best = 0xFFFFFFFFu;
    for (int i = lane; i < NSLOT * 2; i += 64) {
        const unsigned int v = rowtab[(size_t)row * NSLOT * 2 + i];
        vals[nv++] = v;
        best = minu(best, v);
    }
#pragma unroll
    for (int d = 1; d < 64; d <<= 1) best = minu(best, __shfl_xor(best, d));

    const float dmin = unfkey(best & KMASK);
    const unsigned int tkey = fkey(dmin + 4.0f);
    for (int k = 0; k < nv; ++k)
        if ((vals[k] & KMASK) < tkey) {
            const int p = atomicAdd(&ccnt[wave], 1);
            if (p < 64) clist[wave][p] = vals[k] & 8191u;
        }
    __syncthreads();
    int cnt = ccnt[wave];
    cnt = cnt > 64 ? 64 : cnt;

    const float4* xi = (const float4*)(xs + (size_t)row * DIM);
    const float4 x0 = xi[2 * lane], x1 = xi[2 * lane + 1];
    const float sqi = sq[row];
    unsigned long long bestf = ~0ull;
    for (int c = 0; c < cnt; ++c) {
        const unsigned int j = clist[wave][c];
        const float4* xj = (const float4*)(xs + (size_t)j * DIM);
        const float4 y0 = xj[2 * lane], y1 = xj[2 * lane + 1];
        float dot = 0.f;
        dot = fmaf(x0.x, y0.x, dot); dot = fmaf(x0.y, y0.y, dot);
        dot = fmaf(x0.z, y0.z, dot); dot = fmaf(x0.w, y0.w, dot);
        dot = fmaf(x1.x, y1.x, dot); dot = fmaf(x1.y, y1.y, dot);
        dot = fmaf(x1.z, y1.z, dot); dot = fmaf(x1.w, y1.w, dot);
#pragma unroll
        for (int d = 1; d < 64; d <<= 1) dot += __shfl_xor(dot, d);
        const float d2 = sqi + sq[j] - 2.f * dot;
        const unsigned long long pk = (((unsigned long long)fkey(d2)) << 32) | j;
        bestf = min64(bestf, pk);
    }
    if (lane == 0) nn[row] = bestf;
}

// helpers for tail GEMMs
__device__ __forceinline__ void split3(const float* v, u16x8& h8, u16x8& m8, u16x8& l8) {
#pragma unroll
    for (int j = 0; j < 8; ++j) {
        const float x = v[j];
        const unsigned short h = f2bf(x);
        const float r1 = x - bf2f(h);
        const unsigned short m = f2bf(r1);
        const float r2 = r1 - bf2f(m);
        h8[j] = h; m8[j] = m; l8[j] = f2bf(r2);
    }
}
__device__ __forceinline__ void split2(const float* v, u16x8& h8, u16x8& l8) {
#pragma unroll
    for (int j = 0; j < 8; ++j) {
        const float x = v[j];
        const unsigned short h = f2bf(x);
        h8[j] = h; l8[j] = f2bf(x - bf2f(h));
    }
}

// ---------------------------------------------------------------- k_p  (unchanged)
__global__ __launch_bounds__(256) void k_p(const float* __restrict__ xs,
                                           const float* __restrict__ W1,
                                           float* __restrict__ P) {
    __shared__ __align__(16) unsigned short lAh[64 * 32], lAm[64 * 32], lAl[64 * 32];
    __shared__ __align__(16) unsigned short lWh[64 * 32], lWm[64 * 32], lWl[64 * 32];
    const int tid = threadIdx.x, wave = tid >> 6, lane = tid & 63, quad = lane >> 4,
              ln = lane & 15;
    const int i0 = blockIdx.x * 64;
    const int row = tid >> 2, c = tid & 3;
    const int wofs = row * 32 + ((c + (row >> 1)) & 3) * 8;

    f32x4 acc[4];
#pragma unroll
    for (int ns = 0; ns < 4; ++ns) acc[ns] = (f32x4){0.f, 0.f, 0.f, 0.f};

    const int ar = wave * 16 + ln;
    const int aofs = ar * 32 + ((quad + (ar >> 1)) & 3) * 8;
    int bofs[4];
#pragma unroll
    for (int ns = 0; ns < 4; ++ns) {
        const int br = ns * 16 + ln;
        bofs[ns] = br * 32 + ((quad + (br >> 1)) & 3) * 8;
    }

    for (int kt = 0; kt < 16; ++kt) {
        __syncthreads();
        {
            const float* src = xs + (size_t)(i0 + row) * DIM + kt * 32 + c * 8;
            const float4 f0 = *(const float4*)src, f1 = *(const float4*)(src + 4);
            float v[8] = {f0.x, f0.y, f0.z, f0.w, f1.x, f1.y, f1.z, f1.w};
            u16x8 h8, m8, l8;
            split3(v, h8, m8, l8);
            *(u16x8*)(lAh + wofs) = h8;
            *(u16x8*)(lAm + wofs) = m8;
            *(u16x8*)(lAl + wofs) = l8;
        }
        {
            const float* src = W1 + (size_t)row * DIM + kt * 32 + c * 8;
            const float4 f0 = *(const float4*)src, f1 = *(const float4*)(src + 4);
            float v[8] = {f0.x, f0.y, f0.z, f0.w, f1.x, f1.y, f1.z, f1.w};
            u16x8 h8, m8, l8;
            split3(v, h8, m8, l8);
            *(u16x8*)(lWh + wofs) = h8;
            *(u16x8*)(lWm + wofs) = m8;
            *(u16x8*)(lWl + wofs) = l8;
        }
        __syncthreads();
        const bf16x8 ah = *(const bf16x8*)(lAh + aofs);
        const bf16x8 am = *(const bf16x8*)(lAm + aofs);
        const bf16x8 al = *(const bf16x8*)(lAl + aofs);
#pragma unroll
        for (int ns = 0; ns < 4; ++ns) {
            const bf16x8 bh = *(const bf16x8*)(lWh + bofs[ns]);
            const bf16x8 bm = *(const bf16x8*)(lWm + bofs[ns]);
            const bf16x8 bl = *(const bf16x8*)(lWl + bofs[ns]);
            acc[ns] = __builtin_amdgcn_mfma_f32_16x16x32_bf16(ah, bh, acc[ns], 0, 0, 0);
            acc[ns] = __builtin_amdgcn_mfma_f32_16x16x32_bf16(ah, bm, acc[ns], 0, 0, 0);
            acc[ns] = __builtin_amdgcn_mfma_f32_16x16x32_bf16(am, bh, acc[ns], 0, 0, 0);
            acc[ns] = __builtin_amdgcn_mfma_f32_16x16x32_bf16(am, bm, acc[ns], 0, 0, 0);
            acc[ns] = __builtin_amdgcn_mfma_f32_16x16x32_bf16(ah, bl, acc[ns], 0, 0, 0);
            acc[ns] = __builtin_amdgcn_mfma_f32_16x16x32_bf16(al, bh, acc[ns], 0, 0, 0);
        }
    }
#pragma unroll
    for (int ns = 0; ns < 4; ++ns)
#pragma unroll
        for (int v = 0; v < 4; ++v)
            P[(size_t)(i0 + wave * 16 + quad * 4 + v) * 64 + ns * 16 + ln] = acc[ns][v];
}

// ---------------------------------------------------------------- k_tail  (unchanged)
__global__ __launch_bounds__(64) void k_tail(const float* __restrict__ P,
                                             const unsigned long long* __restrict__ nn,
                                             const float* __restrict__ b1,
                                             const float* __restrict__ W2,
                                             const float* __restrict__ b2,
                                             const float* __restrict__ W3,
                                             const float* __restrict__ b3,
                                             const float* __restrict__ D1,
                                             const float* __restrict__ d1,
                                             const float* __restrict__ D2,
                                             const float* __restrict__ d2,
                                             float* __restrict__ out_zs,
                                             float* __restrict__ G2) {
    __shared__ float ls[32 * 64];
    const int lane = threadIdx.x;
    const int row = blockIdx.x * 64 + lane;
    const unsigned int nnr = (unsigned int)(nn[row] & 0xFFFFFFFFull) & 8191u;
    const float* pr = P + (size_t)row * 64;
    const float* p0 = P + (size_t)nnr * 64;

    float h1[64], th1[64];
#pragma unroll
    for (int k = 0; k < 64; k += 4) {
        const float4 a = *(const float4*)(pr + k);
        const float4 b = *(const float4*)(p0 + k);
        const float pv[4] = {a.x, a.y, a.z, a.w}, qv[4] = {b.x, b.y, b.z, b.w};
#pragma unroll
        for (int j = 0; j < 4; ++j) {
            const float a1 = qv[j] + b1[k + j];
            h1[k + j] = fmaxf(a1, 0.f);
            th1[k + j] = (a1 > 0.f) ? (pv[j] - qv[j]) : 0.f;
        }
    }
    for (int o = 0; o < 32; o += 2) {
        float a0 = b2[o], u0 = 0.f, a1v = b2[o + 1], u1v = 0.f;
        const float* w0 = W2 + o * 64;
        const float* w1 = W2 + (o + 1) * 64;
#pragma unroll
        for (int k = 0; k < 64; ++k) {
            a0 = fmaf(h1[k], w0[k], a0);
            u0 = fmaf(th1[k], w0[k], u0);
            a1v = fmaf(h1[k], w1[k], a1v);
            u1v = fmaf(th1[k], w1[k], u1v);
        }
        ls[o * 64 + lane] = fmaxf(a0, 0.f) + ((a0 > 0.f) ? u0 : 0.f);
        ls[(o + 1) * 64 + lane] = fmaxf(a1v, 0.f) + ((a1v > 0.f) ? u1v : 0.f);
    }
    float sv[32];
#pragma unroll
    for (int k = 0; k < 32; ++k) sv[k] = ls[k * 64 + lane];
    for (int o = 0; o < 32; o += 2) {
        float z0 = b3[o], z1 = b3[o + 1];
        const float* w0 = W3 + o * 32;
        const float* w1 = W3 + (o + 1) * 32;
#pragma unroll
        for (int k = 0; k < 32; ++k) {
            z0 = fmaf(sv[k], w0[k], z0);
            z1 = fmaf(sv[k], w1[k], z1);
        }
        out_zs[(size_t)row * 32 + o] = z0;
        out_zs[(size_t)row * 32 + o + 1] = z1;
        ls[o * 64 + lane] = z0;
        ls[(o + 1) * 64 + lane] = z1;
    }
    float zv[32];
#pragma unroll
    for (int k = 0; k < 32; ++k) zv[k] = ls[k * 64 + lane];
    for (int o = 0; o < 32; o += 2) {
        float g0 = d1[o], g1v = d1[o + 1];
        const float* w0 = D1 + o * 32;
        const float* w1 = D1 + (o + 1) * 32;
#pragma unroll
        for (int k = 0; k < 32; ++k) {
            g0 = fmaf(zv[k], w0[k], g0);
            g1v = fmaf(zv[k], w1[k], g1v);
        }
        ls[o * 64 + lane] = fmaxf(g0, 0.f);
        ls[(o + 1) * 64 + lane] = fmaxf(g1v, 0.f);
    }
    float gv[32];
#pragma unroll
    for (int k = 0; k < 32; ++k) gv[k] = ls[k * 64 + lane];
    for (int o = 0; o < 64; o += 2) {
        float g0 = d2[o], g1v = d2[o + 1];
        const float* w0 = D2 + o * 32;
        const float* w1 = D2 + (o + 1) * 32;
#pragma unroll
        for (int k = 0; k < 32; ++k) {
            g0 = fmaf(gv[k], w0[k], g0);
            g1v = fmaf(gv[k], w1[k], g1v);
        }
        G2[(size_t)row * 64 + o] = fmaxf(g0, 0.f);
        G2[(size_t)row * 64 + o + 1] = fmaxf(g1v, 0.f);
    }
}

// ---------------------------------------------------------------- k_dec  (unchanged)
__global__ __launch_bounds__(256) void k_dec(const float* __restrict__ G2,
                                             const float* __restrict__ D3,
                                             const float* __restrict__ d3,
                                             float* __restrict__ xhat) {
    __shared__ __align__(16) unsigned short lGh[128 * 64], lGl[128 * 64];
    __shared__ __align__(16) unsigned short lDh[128 * 64], lDl[128 * 64];
    const int tid = threadIdx.x, wave = tid >> 6, lane = tid & 63, quad = lane >> 4,
              ln = lane & 15;
    const int i0 = blockIdx.x * 128, nbase = blockIdx.y * 128;
    const int m_off = (wave & 1) * 64, n_off = (wave >> 1) * 64;
#pragma unroll
    for (int r = 0; r < 4; ++r) {
        const int g = r * 256 + tid;
        const int row = g >> 3, cIdx = g & 7, half = cIdx >> 2, cc = cIdx & 3;
        const int wofs = row * 64 + half * 32 + ((cc + (row >> 1)) & 3) * 8;
        {
            const float* src = G2 + (size_t)(i0 + row) * 64 + cIdx * 8;
            const float4 f0 = *(const float4*)src, f1 = *(const float4*)(src + 4);
            float v[8] = {f0.x, f0.y, f0.z, f0.w, f1.x, f1.y, f1.z, f1.w};
            u16x8 h8, l8;
            split2(v, h8, l8);
            *(u16x8*)(lGh + wofs) = h8;
            *(u16x8*)(lGl + wofs) = l8;
        }
        {
            const float* src = D3 + (size_t)(nbase + row) * 64 + cIdx * 8;
            const float4 f0 = *(const float4*)src, f1 = *(const float4*)(src + 4);
            float v[8] = {f0.x, f0.y, f0.z, f0.w, f1.x, f1.y, f1.z, f1.w};
            u16x8 h8, l8;
            split2(v, h8, l8);
            *(u16x8*)(lDh + wofs) = h8;
            *(u16x8*)(lDl + wofs) = l8;
        }
    }
    __syncthreads();
    f32x4 acc[4][4];
#pragma unroll
    for (int a = 0; a < 4; ++a)
#pragma unroll
        for (int c = 0; c < 4; ++c) acc[a][c] = (f32x4){0.f, 0.f, 0.f, 0.f};
#pragma unroll
    for (int kk = 0; kk < 2; ++kk) {
        bf16x8 ah[4], al[4], bh[4], bl[4];
#pragma unroll
        for (int ms = 0; ms < 4; ++ms) {
            const int ar = m_off + ms * 16 + ln;
            const int aofs = ar * 64 + kk * 32 + ((quad + (ar >> 1)) & 3) * 8;
            ah[ms] = *(const bf16x8*)(lGh + aofs);
            al[ms] = *(const bf16x8*)(lGl + aofs);
        }
#pragma unroll
        for (int ns = 0; ns < 4; ++ns) {
            const int br = n_off + ns * 16 + ln;
            const int bofs = br * 64 + kk * 32 + ((quad + (br >> 1)) & 3) * 8;
            bh[ns] = *(const bf16x8*)(lDh + bofs);
            bl[ns] = *(const bf16x8*)(lDl + bofs);
        }
#pragma unroll
        for (int ms = 0; ms < 4; ++ms)
#pragma unroll
            for (int ns = 0; ns < 4; ++ns) {
                acc[ms][ns] = __builtin_amdgcn_mfma_f32_16x16x32_bf16(
                    ah[ms], bh[ns], acc[ms][ns], 0, 0, 0);
                acc[ms][ns] = __builtin_amdgcn_mfma_f32_16x16x32_bf16(
                    ah[ms], bl[ns], acc[ms][ns], 0, 0, 0);
                acc[ms][ns] = __builtin_amdgcn_mfma_f32_16x16x32_bf16(
                    al[ms], bh[ns], acc[ms][ns], 0, 0, 0);
            }
    }
    float d3f[4];
#pragma unroll
    for (int ns = 0; ns < 4; ++ns) d3f[ns] = d3[nbase + n_off + ns * 16 + ln];
#pragma unroll
    for (int ms = 0; ms < 4; ++ms)
#pragma unroll
        for (int ns = 0; ns < 4; ++ns)
#pragma unroll
            for (int v = 0; v < 4; ++v) {
                const int m = m_off + ms * 16 + quad * 4 + v;
                const int n = n_off + ns * 16 + ln;
                xhat[(size_t)(i0 + m) * DIM + nbase + n] = acc[ms][ns][v] + d3f[ns];
            }
}

extern "C" void kernel_launch(void* const* d_in, const int* in_sizes, int n_in,
                              void* d_out, int out_size, void* d_ws, size_t ws_size,
                              hipStream_t stream) {
    const float* xs = (const float*)d_in[0];
    const float* W1 = (const float*)d_in[1];
    const float* b1 = (const float*)d_in[2];
    const float* W2 = (const float*)d_in[3];
    const float* b2 = (const float*)d_in[4];
    const float* W3 = (const float*)d_in[5];
    const float* b3 = (const float*)d_in[6];
    const float* D1 = (const float*)d_in[7];
    const float* d1 = (const float*)d_in[8];
    const float* D2 = (const float*)d_in[9];
    const float* d2 = (const float*)d_in[10];
    const float* D3 = (const float*)d_in[11];
    const float* d3 = (const float*)d_in[12];

    // ws (12.7 MB, proven-safe layout): sq | nn | xs_hi | P | G2
    char* ws = (char*)d_ws;
    float* sq = (float*)(ws);                                     // 32 KB
    unsigned long long* nn = (unsigned long long*)(ws + 32768);   // 64 KB
    unsigned short* xs_hi = (unsigned short*)(ws + 131072);       // 8 MB
    float* P = (float*)(ws + 8519680);                            // 2 MB
    float* G2 = (float*)(ws + 10616832);                          // 2 MB

    float* xhat = (float*)d_out;
    float* zs = (float*)d_out + (size_t)NROWS * DIM;
    // rowtab scratch (u32, 8.5 MB) lives in d_out's dead space
    unsigned int* rowtab = (unsigned int*)d_out;

    hipLaunchKernelGGL(k_prep, dim3(2048), dim3(256), 0, stream, xs, xs_hi, sq);
    hipLaunchKernelGGL(k_nn, dim3(2112), dim3(256), 0, stream, xs_hi, sq, rowtab);
    hipLaunchKernelGGL(k_refine, dim3(2048), dim3(256), 0, stream, rowtab, xs, sq, nn);
    hipLaunchKernelGGL(k_p, dim3(128), dim3(256), 0, stream, xs, W1, P);
    hipLaunchKernelGGL(k_tail, dim3(128), dim3(64), 0, stream, P, nn, b1, W2, b2, W3,
                       b3, D1, d1, D2, d2, zs, G2);
    hipLaunchKernelGGL(k_dec, dim3(64, 4), dim3(256), 0, stream, G2, D3, d3, xhat);
}